// Round 7
// baseline (88.603 us; speedup 1.0000x reference)
//
#include <hip/hip_runtime.h>
#include <hip/hip_bf16.h>

#define CELLS 1000   // 10*10*10
#define DPB   50     // depos per block -> 2000 blocks, ~200KB contiguous stores/block
#define NTH   256

// 256-thread blocks, 50 depos per block.
// Phase 1: 1500 (depo,dim,k) tasks over 256 threads (~6 each, 2 erfs per task)
//          -> w[d][dim*10+k] in LDS; k==0 writes offsets; r==0 stages charge.
// Store  : threads 0..249 own fixed c4 (invariant LDS indices), iterate the 50
//          depos -> one contiguous 200KB float4 store stream per block, one
//          barrier per 200KB. 8 blocks/CU resident, staggered -> continuous
//          per-CU store duty cycle (the variable under test).
__global__ __launch_bounds__(NTH) void raster_kernel(
    const float* __restrict__ sigma,   // [N,3]
    const float* __restrict__ time,    // [N]
    const float* __restrict__ charge,  // [N]
    const float* __restrict__ tail,    // [N,3]
    const float* __restrict__ gs,      // [3]
    const float* __restrict__ nsig,    // [1]
    float* __restrict__ out_r,         // [N,10,10,10]
    float* __restrict__ out_off,       // [N,3] (int values stored as f32)
    int n)
{
    const int d0  = blockIdx.x * DPB;
    const int tid = threadIdx.x;

    __shared__ float wq[DPB][32];   // [d][0..29]=w, [30]=charge

    // ---- phase 1 ----
#pragma unroll
    for (int idx = tid; idx < DPB * 30; idx += NTH) {
        const int d   = idx / 30;
        const int r   = idx - d * 30;
        const int dim = r / 10;
        const int k   = r - dim * 10;
        const int depo = d0 + d;
        if (depo < n) {
            float c;
            if (dim == 0)      c = tail[depo * 3 + 1];
            else if (dim == 1) c = tail[depo * 3 + 2];
            else               c = time[depo];
            const float sg = sigma[depo * 3 + dim];
            const float sp = gs[dim];
            const float ns = nsig[0];
            const float imin = floorf((c - ns * sg) / sp);
            const float inv  = 1.0f / (1.41421356237309f * sg);
            const float e0   = (imin + (float)k) * sp;
            const float cdf0 = 0.5f * (1.0f + erff((e0 - c) * inv));
            const float cdf1 = 0.5f * (1.0f + erff((e0 + sp - c) * inv));
            wq[d][dim * 10 + k] = cdf1 - cdf0;
            if (k == 0) {
                out_off[(size_t)depo * 3 + dim] = (float)(int)imin;
                if (dim == 0) wq[d][30] = charge[depo];
            }
        }
    }
    __syncthreads();

    // ---- store phase: 50 x 4KB contiguous ----
    if (tid < 250) {
        const int c4 = tid;                  // float4 index within a depo
        int a0[4], a1[4], a2[4];             // invariant component indices
#pragma unroll
        for (int c = 0; c < 4; ++c) {
            const int cell = c4 * 4 + c;
            a0[c] = cell / 100;
            a1[c] = 10 + (cell / 10) % 10;
            a2[c] = 20 + cell % 10;
        }

        for (int d = 0; d < DPB; ++d) {
            const int depo = d0 + d;
            if (depo < n) {
                const float q = wq[d][30];
                float4 v;
                v.x = q * wq[d][a0[0]] * wq[d][a1[0]] * wq[d][a2[0]];
                v.y = q * wq[d][a0[1]] * wq[d][a1[1]] * wq[d][a2[1]];
                v.z = q * wq[d][a0[2]] * wq[d][a1[2]] * wq[d][a2[2]];
                v.w = q * wq[d][a0[3]] * wq[d][a1[3]] * wq[d][a2[3]];
                float4* dst = reinterpret_cast<float4*>(out_r + (size_t)depo * CELLS) + c4;
                *dst = v;
            }
        }
    }
}

extern "C" void kernel_launch(void* const* d_in, const int* in_sizes, int n_in,
                              void* d_out, int out_size, void* d_ws, size_t ws_size,
                              hipStream_t stream) {
    const float* sigma  = (const float*)d_in[0];  // [N,3]
    const float* time_  = (const float*)d_in[1];  // [N]
    const float* charge = (const float*)d_in[2];  // [N]
    const float* tail   = (const float*)d_in[3];  // [N,3]
    const float* gs     = (const float*)d_in[4];  // [3]
    const float* nsig   = (const float*)d_in[5];  // [1]

    const int n = in_sizes[1];  // time has N elements

    float* out_r   = (float*)d_out;                       // N*1000 floats
    float* out_off = (float*)d_out + (size_t)n * CELLS;   // N*3 values

    const int grid = (n + DPB - 1) / DPB;
    raster_kernel<<<grid, NTH, 0, stream>>>(sigma, time_, charge, tail, gs, nsig,
                                            out_r, out_off, n);
}

// Round 8
// 82.992 us; speedup vs baseline: 1.0676x; 1.0676x over previous
//
#include <hip/hip_runtime.h>
#include <hip/hip_bf16.h>

#define CELLS 1000     // 10*10*10
#define NTH   256      // 4 waves per block
#define WPB   4
#define NBLK  2048     // 8192 waves persistent

// Wave-autonomous, zero-barrier kernel. Each wave processes one depo-PAIR per
// iteration: lanes 0..59 compute w[2][30] (2 erfs each) into this wave's
// private LDS slice (wave-synchronous: in-order ds ops + compiler lgkmcnt --
// no __syncthreads anywhere), then all 64 lanes issue 8 coalesced float4
// store-instrs (8 KB). 32 independent waves/CU at random phases keep the
// per-CU store stream continuous (the variable under test: store duty cycle).
__global__ __launch_bounds__(NTH) void raster_kernel(
    const float* __restrict__ sigma,   // [N,3]
    const float* __restrict__ time,    // [N]
    const float* __restrict__ charge,  // [N]
    const float* __restrict__ tail,    // [N,3]
    const float* __restrict__ gs,      // [3]
    const float* __restrict__ nsig,    // [1]
    float* __restrict__ out_r,         // [N,10,10,10]
    float* __restrict__ out_off,       // [N,3] (int values stored as f32)
    int n)
{
    const int tid  = threadIdx.x;
    const int lane = tid & 63;
    const int wv   = tid >> 6;

    __shared__ float wq[WPB][2][32];   // per-wave slice: [pairidx][0..29]=w,[30]=q

    // fixed compute role (lanes 0..59)
    const bool cp  = (lane < 60);
    const int  cd  = lane / 30;        // which depo of the pair
    const int  r   = cp ? (lane - cd * 30) : 0;
    const int  dim = r / 10;
    const int  k   = r - dim * 10;

    const float ns = nsig[0];
    const float sp = gs[cp ? dim : 0];

    const int npairs  = (n + 1) >> 1;
    const int stride  = gridDim.x * WPB;
    int p = blockIdx.x * WPB + wv;

    for (; p < npairs; p += stride) {
        const int d0 = p * 2;

        // ---- compute phase (this wave only) ----
        if (cp) {
            const int depo = d0 + cd;
            if (depo < n) {
                float c;
                if (dim == 0)      c = tail[depo * 3 + 1];
                else if (dim == 1) c = tail[depo * 3 + 2];
                else               c = time[depo];
                const float sg   = sigma[depo * 3 + dim];
                const float imin = floorf((c - ns * sg) / sp);
                const float inv  = 1.0f / (1.41421356237309f * sg);
                const float e0   = (imin + (float)k) * sp;
                const float cdf0 = 0.5f * (1.0f + erff((e0 - c) * inv));
                const float cdf1 = 0.5f * (1.0f + erff((e0 + sp - c) * inv));
                wq[wv][cd][dim * 10 + k] = cdf1 - cdf0;
                if (k == 0) {
                    out_off[(size_t)depo * 3 + dim] = (float)(int)imin;
                    if (dim == 0) wq[wv][cd][30] = charge[depo];
                }
            }
        }
        // no barrier: same-wave LDS ops are in-order; compiler emits lgkmcnt.

        // ---- store phase: 8 coalesced float4 instrs = 8 KB ----
#pragma unroll
        for (int s = 0; s < 8; ++s) {
            const int idx = s * 64 + lane;        // 0..511, 500 used
            if (idx < 500) {
                const int dd   = idx / 250;       // depo within pair
                const int c4   = idx - dd * 250;  // float4 index in depo
                const int depo = d0 + dd;
                if (depo < n) {
                    const float q = wq[wv][dd][30];
                    float4 v;
                    {
                        const int cell = c4 * 4 + 0;
                        v.x = q * wq[wv][dd][cell / 100]
                                * wq[wv][dd][10 + (cell / 10) % 10]
                                * wq[wv][dd][20 + cell % 10];
                    }
                    {
                        const int cell = c4 * 4 + 1;
                        v.y = q * wq[wv][dd][cell / 100]
                                * wq[wv][dd][10 + (cell / 10) % 10]
                                * wq[wv][dd][20 + cell % 10];
                    }
                    {
                        const int cell = c4 * 4 + 2;
                        v.z = q * wq[wv][dd][cell / 100]
                                * wq[wv][dd][10 + (cell / 10) % 10]
                                * wq[wv][dd][20 + cell % 10];
                    }
                    {
                        const int cell = c4 * 4 + 3;
                        v.w = q * wq[wv][dd][cell / 100]
                                * wq[wv][dd][10 + (cell / 10) % 10]
                                * wq[wv][dd][20 + cell % 10];
                    }
                    float4* dst =
                        reinterpret_cast<float4*>(out_r + (size_t)depo * CELLS) + c4;
                    *dst = v;
                }
            }
        }
    }
}

extern "C" void kernel_launch(void* const* d_in, const int* in_sizes, int n_in,
                              void* d_out, int out_size, void* d_ws, size_t ws_size,
                              hipStream_t stream) {
    const float* sigma  = (const float*)d_in[0];  // [N,3]
    const float* time_  = (const float*)d_in[1];  // [N]
    const float* charge = (const float*)d_in[2];  // [N]
    const float* tail   = (const float*)d_in[3];  // [N,3]
    const float* gs     = (const float*)d_in[4];  // [3]
    const float* nsig   = (const float*)d_in[5];  // [1]

    const int n = in_sizes[1];  // time has N elements

    float* out_r   = (float*)d_out;                       // N*1000 floats
    float* out_off = (float*)d_out + (size_t)n * CELLS;   // N*3 values

    const int npairs = (n + 1) >> 1;
    int grid = (npairs + WPB - 1) / WPB;
    if (grid > NBLK) grid = NBLK;
    raster_kernel<<<grid, NTH, 0, stream>>>(sigma, time_, charge, tail, gs, nsig,
                                            out_r, out_off, n);
}